// Round 1
// baseline (272.640 us; speedup 1.0000x reference)
//
#include <hip/hip_runtime.h>
#include <hip/hip_bf16.h>
#include <cstdint>

#define B_ 2
#define C_ 128
#define E_ 60000

// ---------------------------------------------------------------------------
// Kernel 0: fold the 256->3 fuse conv into the per-path weights.
// Vw layout: [p][j][s][c] flat, p=path(a,b), j=0..2, s=0..4 (s=0 absorbs local)
// cst[j] = all bias contributions.
// ---------------------------------------------------------------------------
__global__ __launch_bounds__(256) void fuse_weights_kernel(
    const float* __restrict__ Wa_local, const float* __restrict__ ba_local,
    const float* __restrict__ Wb_local, const float* __restrict__ bb_local,
    const float* __restrict__ Wa_tri,  const float* __restrict__ ba_tri,
    const float* __restrict__ Wb_tri,  const float* __restrict__ bb_tri,
    const float* __restrict__ Wa_fuse, const float* __restrict__ ba_fuse,
    const float* __restrict__ Wb_fuse, const float* __restrict__ bb_fuse,
    float* __restrict__ Vw, float* __restrict__ cst)
{
    int t = blockIdx.x * 256 + threadIdx.x;
    if (t < 2 * 3 * 5 * C_) {
        int c = t & (C_ - 1);
        int r = t >> 7;          // (p*3+j)*5+s
        int s = r % 5; r /= 5;
        int j = r % 3;
        int p = r / 3;
        const float* Wf = p ? Wb_fuse : Wa_fuse;   // [3][256]
        const float* Wt = p ? Wb_tri  : Wa_tri;    // [128][128][5]
        const float* Wl = p ? Wb_local : Wa_local; // [128][128]
        float acc = 0.f;
        for (int o = 0; o < C_; ++o)
            acc += Wf[j * 256 + 128 + o] * Wt[(o * C_ + c) * 5 + s];
        if (s == 0)
            for (int o = 0; o < C_; ++o)
                acc += Wf[j * 256 + o] * Wl[o * C_ + c];
        Vw[t] = acc;
    } else if (t < 2 * 3 * 5 * C_ + 3) {
        int j = t - 2 * 3 * 5 * C_;
        float acc = ba_fuse[j] + bb_fuse[j];
        for (int o = 0; o < C_; ++o) {
            acc += Wa_fuse[j * 256 + o]       * ba_local[o]
                 + Wa_fuse[j * 256 + 128 + o] * ba_tri[o]
                 + Wb_fuse[j * 256 + o]       * bb_local[o]
                 + Wb_fuse[j * 256 + 128 + o] * bb_tri[o];
        }
        cst[j] = acc;
    }
}

// ---------------------------------------------------------------------------
// Kernel 1: transpose [B,C,E] -> [B,E,C] for both x0 and x1 (grid.z selects).
// 32x32 LDS tile, padded to kill bank conflicts. Both sides coalesced.
// ---------------------------------------------------------------------------
__global__ __launch_bounds__(256) void transpose_kernel(
    const float* __restrict__ x0, const float* __restrict__ x1,
    float* __restrict__ x0t, float* __restrict__ x1t)
{
    __shared__ float tile[32][33];
    const int which = blockIdx.z >> 1;   // 0 -> x0, 1 -> x1
    const int b     = blockIdx.z & 1;
    const float* src = (which ? x1 : x0) + (size_t)b * C_ * E_;
    float*       dst = (which ? x1t : x0t) + (size_t)b * E_ * C_;
    const int e0 = blockIdx.x * 32;
    const int c0 = blockIdx.y * 32;
    const int tx = threadIdx.x & 31;
    const int ty = threadIdx.x >> 5;     // 0..7
#pragma unroll
    for (int i = 0; i < 32; i += 8)
        tile[ty + i][tx] = src[(size_t)(c0 + ty + i) * E_ + e0 + tx];
    __syncthreads();
#pragma unroll
    for (int i = 0; i < 32; i += 8)
        dst[(size_t)(e0 + ty + i) * C_ + c0 + tx] = tile[tx][ty + i];
}

// ---------------------------------------------------------------------------
// Kernel 2: fused gather + features + 3-channel projection.
// One wave per edge (grid-stride). lane = channel pair (float2 loads, 512 B
// contiguous per vector gather). 60 FMAs/lane, then 3-value wave reduce.
// ---------------------------------------------------------------------------
__global__ __launch_bounds__(256) void mesh_fused_kernel(
    const float* __restrict__ x0t, const float* __restrict__ x1t,
    const int* __restrict__ gemm, const float* __restrict__ Vw,
    const float* __restrict__ cst, float* __restrict__ out)
{
    const int lane = threadIdx.x & 63;
    const int wv   = threadIdx.x >> 6;
    const int gw   = blockIdx.x * 4 + wv;
    const int nw   = gridDim.x * 4;
    const int co   = lane * 2;

    // per-lane fused weights for its two channels: 2 paths x 3 j x 5 s
    float2 w[2][3][5];
#pragma unroll
    for (int p = 0; p < 2; ++p)
#pragma unroll
        for (int j = 0; j < 3; ++j)
#pragma unroll
            for (int s = 0; s < 5; ++s)
                w[p][j][s] = *(const float2*)(Vw + (((p * 3 + j) * 5 + s) << 7) + co);
    const float c0 = cst[0], c1 = cst[1], c2 = cst[2];

    for (int edge = gw; edge < B_ * E_; edge += nw) {
        const int b = edge >= E_;
        const int e = edge - b * E_;
        const int4 gi = *(const int4*)(gemm + (edge << 2));
        const float* xa = x0t + ((size_t)b * E_) * C_;
        const float* xb = x1t + ((size_t)b * E_) * C_;

        float2 a0 = *(const float2*)(xa + ((size_t)e    << 7) + co);
        float2 a1 = *(const float2*)(xa + ((size_t)gi.x << 7) + co);
        float2 a2 = *(const float2*)(xa + ((size_t)gi.y << 7) + co);
        float2 a3 = *(const float2*)(xa + ((size_t)gi.z << 7) + co);
        float2 a4 = *(const float2*)(xa + ((size_t)gi.w << 7) + co);
        float2 b0 = *(const float2*)(xb + ((size_t)e    << 7) + co);
        float2 b1 = *(const float2*)(xb + ((size_t)gi.x << 7) + co);
        float2 b2 = *(const float2*)(xb + ((size_t)gi.y << 7) + co);
        float2 b3 = *(const float2*)(xb + ((size_t)gi.z << 7) + co);
        float2 b4 = *(const float2*)(xb + ((size_t)gi.w << 7) + co);

        float2 sa1 = {a1.x + a3.x, a1.y + a3.y};
        float2 sa2 = {a2.x + a4.x, a2.y + a4.y};
        float2 da1 = {fabsf(a1.x - a3.x), fabsf(a1.y - a3.y)};
        float2 da2 = {fabsf(a2.x - a4.x), fabsf(a2.y - a4.y)};
        float2 sb1 = {b1.x + b3.x, b1.y + b3.y};
        float2 sb2 = {b2.x + b4.x, b2.y + b4.y};
        float2 db1 = {fabsf(b1.x - b3.x), fabsf(b1.y - b3.y)};
        float2 db2 = {fabsf(b2.x - b4.x), fabsf(b2.y - b4.y)};

        float acc[3];
#pragma unroll
        for (int j = 0; j < 3; ++j) {
            float t;
            t  = w[0][j][0].x * a0.x  + w[0][j][0].y * a0.y;
            t += w[0][j][1].x * sa1.x + w[0][j][1].y * sa1.y;
            t += w[0][j][2].x * sa2.x + w[0][j][2].y * sa2.y;
            t += w[0][j][3].x * da1.x + w[0][j][3].y * da1.y;
            t += w[0][j][4].x * da2.x + w[0][j][4].y * da2.y;
            t += w[1][j][0].x * b0.x  + w[1][j][0].y * b0.y;
            t += w[1][j][1].x * sb1.x + w[1][j][1].y * sb1.y;
            t += w[1][j][2].x * sb2.x + w[1][j][2].y * sb2.y;
            t += w[1][j][3].x * db1.x + w[1][j][3].y * db1.y;
            t += w[1][j][4].x * db2.x + w[1][j][4].y * db2.y;
            acc[j] = t;
        }

#pragma unroll
        for (int off = 32; off > 0; off >>= 1) {
            acc[0] += __shfl_xor(acc[0], off, 64);
            acc[1] += __shfl_xor(acc[1], off, 64);
            acc[2] += __shfl_xor(acc[2], off, 64);
        }

        if (lane == 0) {
            float* o = out + (size_t)b * 3 * E_ + e;
            o[0]        = acc[0] + c0;
            o[E_]       = acc[1] + c1;
            o[2 * E_]   = acc[2] + c2;
        }
    }
}

extern "C" void kernel_launch(void* const* d_in, const int* in_sizes, int n_in,
                              void* d_out, int out_size, void* d_ws, size_t ws_size,
                              hipStream_t stream) {
    const float* x0       = (const float*)d_in[0];
    const float* x1       = (const float*)d_in[1];
    const int*   gemm     = (const int*)d_in[2];
    const float* Wa_local = (const float*)d_in[3];
    const float* ba_local = (const float*)d_in[4];
    const float* Wb_local = (const float*)d_in[5];
    const float* bb_local = (const float*)d_in[6];
    const float* Wa_tri   = (const float*)d_in[7];
    const float* ba_tri   = (const float*)d_in[8];
    const float* Wb_tri   = (const float*)d_in[9];
    const float* bb_tri   = (const float*)d_in[10];
    const float* Wa_fuse  = (const float*)d_in[11];
    const float* ba_fuse  = (const float*)d_in[12];
    const float* Wb_fuse  = (const float*)d_in[13];
    const float* bb_fuse  = (const float*)d_in[14];
    float* out = (float*)d_out;

    float* x0t = (float*)d_ws;                       // B*E*C floats
    float* x1t = x0t + (size_t)B_ * E_ * C_;         // B*E*C floats
    float* Vw  = x1t + (size_t)B_ * E_ * C_;         // 2*3*5*128 floats
    float* cst = Vw + 2 * 3 * 5 * C_;                // 3 floats

    hipLaunchKernelGGL(fuse_weights_kernel, dim3(16), dim3(256), 0, stream,
                       Wa_local, ba_local, Wb_local, bb_local,
                       Wa_tri, ba_tri, Wb_tri, bb_tri,
                       Wa_fuse, ba_fuse, Wb_fuse, bb_fuse, Vw, cst);

    hipLaunchKernelGGL(transpose_kernel, dim3(E_ / 32, C_ / 32, 2 * B_),
                       dim3(256), 0, stream, x0, x1, x0t, x1t);

    hipLaunchKernelGGL(mesh_fused_kernel, dim3(1024), dim3(256), 0, stream,
                       x0t, x1t, gemm, Vw, cst, out);
}

// Round 2
// 244.941 us; speedup vs baseline: 1.1131x; 1.1131x over previous
//
#include <hip/hip_runtime.h>
#include <hip/hip_bf16.h>
#include <cstdint>

#define B_ 2
#define C_ 128
#define E_ 60000

typedef unsigned int uint32_;
typedef unsigned short ushort_;

// unpack two bf16 (packed in a dword, low = ch0, high = ch1) to float2
__device__ __forceinline__ float2 bpair(uint32_ v) {
    union { uint32_ u; float f; } lo, hi;
    lo.u = v << 16;
    hi.u = v & 0xffff0000u;
    return make_float2(lo.f, hi.f);
}

// float -> bf16 round-to-nearest-even
__device__ __forceinline__ ushort_ f2b(float f) {
    union { float f; uint32_ u; } x; x.f = f;
    uint32_ u = x.u + 0x7fffu + ((x.u >> 16) & 1u);
    return (ushort_)(u >> 16);
}

// ---------------------------------------------------------------------------
// Kernel 0: fold the 256->3 fuse conv into per-path weights.
// Vw layout: [p][j][s][c] flat (s=0 absorbs the local conv). cst[j] = biases.
// ---------------------------------------------------------------------------
__global__ __launch_bounds__(256) void fuse_weights_kernel(
    const float* __restrict__ Wa_local, const float* __restrict__ ba_local,
    const float* __restrict__ Wb_local, const float* __restrict__ bb_local,
    const float* __restrict__ Wa_tri,  const float* __restrict__ ba_tri,
    const float* __restrict__ Wb_tri,  const float* __restrict__ bb_tri,
    const float* __restrict__ Wa_fuse, const float* __restrict__ ba_fuse,
    const float* __restrict__ Wb_fuse, const float* __restrict__ bb_fuse,
    float* __restrict__ Vw, float* __restrict__ cst)
{
    int t = blockIdx.x * 256 + threadIdx.x;
    if (t < 2 * 3 * 5 * C_) {
        int c = t & (C_ - 1);
        int r = t >> 7;          // (p*3+j)*5+s
        int s = r % 5; r /= 5;
        int j = r % 3;
        int p = r / 3;
        const float* Wf = p ? Wb_fuse : Wa_fuse;   // [3][256]
        const float* Wt = p ? Wb_tri  : Wa_tri;    // [128][128][5]
        const float* Wl = p ? Wb_local : Wa_local; // [128][128]
        float acc = 0.f;
        for (int o = 0; o < C_; ++o)
            acc += Wf[j * 256 + 128 + o] * Wt[(o * C_ + c) * 5 + s];
        if (s == 0)
            for (int o = 0; o < C_; ++o)
                acc += Wf[j * 256 + o] * Wl[o * C_ + c];
        Vw[t] = acc;
    } else if (t < 2 * 3 * 5 * C_ + 3) {
        int j = t - 2 * 3 * 5 * C_;
        float acc = ba_fuse[j] + bb_fuse[j];
        for (int o = 0; o < C_; ++o) {
            acc += Wa_fuse[j * 256 + o]       * ba_local[o]
                 + Wa_fuse[j * 256 + 128 + o] * ba_tri[o]
                 + Wb_fuse[j * 256 + o]       * bb_local[o]
                 + Wb_fuse[j * 256 + 128 + o] * bb_tri[o];
        }
        cst[j] = acc;
    }
}

// ---------------------------------------------------------------------------
// Kernel 1: transpose+quantize [B,C,E] f32 -> [B,E,C] bf16.
// float4 coalesced reads, ushort4 coalesced writes, LDS 32x33 tile.
// ---------------------------------------------------------------------------
__global__ __launch_bounds__(256) void transpose_bf16_kernel(
    const float* __restrict__ x0, const float* __restrict__ x1,
    ushort_* __restrict__ x0t, ushort_* __restrict__ x1t)
{
    __shared__ float tile[32][33];
    const int which = blockIdx.z >> 1;   // 0 -> x0, 1 -> x1
    const int b     = blockIdx.z & 1;
    const float* src = (which ? x1 : x0) + (size_t)b * C_ * E_;
    ushort_*     dst = (which ? x1t : x0t) + (size_t)b * E_ * C_;
    const int e0 = blockIdx.x * 32;
    const int c0 = blockIdx.y * 32;
    const int t  = threadIdx.x;
    {
        const int c = t >> 3, e4 = (t & 7) * 4;
        float4 v = *(const float4*)(src + (size_t)(c0 + c) * E_ + e0 + e4);
        tile[c][e4]     = v.x;
        tile[c][e4 + 1] = v.y;
        tile[c][e4 + 2] = v.z;
        tile[c][e4 + 3] = v.w;
    }
    __syncthreads();
    {
        const int e = t >> 3, c4 = (t & 7) * 4;
        ushort4 w;
        w.x = f2b(tile[c4][e]);
        w.y = f2b(tile[c4 + 1][e]);
        w.z = f2b(tile[c4 + 2][e]);
        w.w = f2b(tile[c4 + 3][e]);
        *(ushort4*)(dst + (size_t)(e0 + e) * C_ + c0 + c4) = w;
    }
}

// ---------------------------------------------------------------------------
// Kernel 2: fused gather + features + 3-channel projection.
// One wave per edge (grid-stride, grid sized for full occupancy).
// lane = channel pair: dword bf16-pair gathers (256 B contiguous per vector).
// ---------------------------------------------------------------------------
__global__ __launch_bounds__(256) void mesh_fused_kernel(
    const ushort_* __restrict__ x0t, const ushort_* __restrict__ x1t,
    const int* __restrict__ gemm, const float* __restrict__ Vw,
    const float* __restrict__ cst, float* __restrict__ out)
{
    const int lane = threadIdx.x & 63;
    const int wv   = threadIdx.x >> 6;
    const int gw   = blockIdx.x * 4 + wv;
    const int nw   = gridDim.x * 4;
    const int co   = lane * 2;

    float2 w[2][3][5];
#pragma unroll
    for (int p = 0; p < 2; ++p)
#pragma unroll
        for (int j = 0; j < 3; ++j)
#pragma unroll
            for (int s = 0; s < 5; ++s)
                w[p][j][s] = *(const float2*)(Vw + (((p * 3 + j) * 5 + s) << 7) + co);
    const float c0 = cst[0], c1 = cst[1], c2 = cst[2];

    for (int edge = gw; edge < B_ * E_; edge += nw) {
        const int b = edge >= E_;
        const int e = edge - b * E_;
        const int4 gi = *(const int4*)(gemm + (edge << 2));
        const ushort_* xa = x0t + (size_t)b * E_ * C_;
        const ushort_* xb = x1t + (size_t)b * E_ * C_;

        uint32_ va0 = *(const uint32_*)(xa + (e    << 7) + co);
        uint32_ va1 = *(const uint32_*)(xa + (gi.x << 7) + co);
        uint32_ va2 = *(const uint32_*)(xa + (gi.y << 7) + co);
        uint32_ va3 = *(const uint32_*)(xa + (gi.z << 7) + co);
        uint32_ va4 = *(const uint32_*)(xa + (gi.w << 7) + co);
        uint32_ vb0 = *(const uint32_*)(xb + (e    << 7) + co);
        uint32_ vb1 = *(const uint32_*)(xb + (gi.x << 7) + co);
        uint32_ vb2 = *(const uint32_*)(xb + (gi.y << 7) + co);
        uint32_ vb3 = *(const uint32_*)(xb + (gi.z << 7) + co);
        uint32_ vb4 = *(const uint32_*)(xb + (gi.w << 7) + co);

        float2 a0 = bpair(va0), a1 = bpair(va1), a2 = bpair(va2),
               a3 = bpair(va3), a4 = bpair(va4);
        float2 b0 = bpair(vb0), b1 = bpair(vb1), b2 = bpair(vb2),
               b3 = bpair(vb3), b4 = bpair(vb4);

        float2 sa1 = {a1.x + a3.x, a1.y + a3.y};
        float2 sa2 = {a2.x + a4.x, a2.y + a4.y};
        float2 da1 = {fabsf(a1.x - a3.x), fabsf(a1.y - a3.y)};
        float2 da2 = {fabsf(a2.x - a4.x), fabsf(a2.y - a4.y)};
        float2 sb1 = {b1.x + b3.x, b1.y + b3.y};
        float2 sb2 = {b2.x + b4.x, b2.y + b4.y};
        float2 db1 = {fabsf(b1.x - b3.x), fabsf(b1.y - b3.y)};
        float2 db2 = {fabsf(b2.x - b4.x), fabsf(b2.y - b4.y)};

        float acc[3];
#pragma unroll
        for (int j = 0; j < 3; ++j) {
            float t;
            t  = w[0][j][0].x * a0.x  + w[0][j][0].y * a0.y;
            t += w[0][j][1].x * sa1.x + w[0][j][1].y * sa1.y;
            t += w[0][j][2].x * sa2.x + w[0][j][2].y * sa2.y;
            t += w[0][j][3].x * da1.x + w[0][j][3].y * da1.y;
            t += w[0][j][4].x * da2.x + w[0][j][4].y * da2.y;
            t += w[1][j][0].x * b0.x  + w[1][j][0].y * b0.y;
            t += w[1][j][1].x * sb1.x + w[1][j][1].y * sb1.y;
            t += w[1][j][2].x * sb2.x + w[1][j][2].y * sb2.y;
            t += w[1][j][3].x * db1.x + w[1][j][3].y * db1.y;
            t += w[1][j][4].x * db2.x + w[1][j][4].y * db2.y;
            acc[j] = t;
        }

#pragma unroll
        for (int off = 32; off > 0; off >>= 1) {
            acc[0] += __shfl_xor(acc[0], off, 64);
            acc[1] += __shfl_xor(acc[1], off, 64);
            acc[2] += __shfl_xor(acc[2], off, 64);
        }

        if (lane == 0) {
            float* o = out + (size_t)b * 3 * E_ + e;
            o[0]      = acc[0] + c0;
            o[E_]     = acc[1] + c1;
            o[2 * E_] = acc[2] + c2;
        }
    }
}

extern "C" void kernel_launch(void* const* d_in, const int* in_sizes, int n_in,
                              void* d_out, int out_size, void* d_ws, size_t ws_size,
                              hipStream_t stream) {
    const float* x0       = (const float*)d_in[0];
    const float* x1       = (const float*)d_in[1];
    const int*   gemm     = (const int*)d_in[2];
    const float* Wa_local = (const float*)d_in[3];
    const float* ba_local = (const float*)d_in[4];
    const float* Wb_local = (const float*)d_in[5];
    const float* bb_local = (const float*)d_in[6];
    const float* Wa_tri   = (const float*)d_in[7];
    const float* ba_tri   = (const float*)d_in[8];
    const float* Wb_tri   = (const float*)d_in[9];
    const float* bb_tri   = (const float*)d_in[10];
    const float* Wa_fuse  = (const float*)d_in[11];
    const float* ba_fuse  = (const float*)d_in[12];
    const float* Wb_fuse  = (const float*)d_in[13];
    const float* bb_fuse  = (const float*)d_in[14];
    float* out = (float*)d_out;

    ushort_* x0t = (ushort_*)d_ws;                    // B*E*C bf16
    ushort_* x1t = x0t + (size_t)B_ * E_ * C_;        // B*E*C bf16
    float*   Vw  = (float*)(x1t + (size_t)B_ * E_ * C_);
    float*   cst = Vw + 2 * 3 * 5 * C_;

    hipLaunchKernelGGL(fuse_weights_kernel, dim3(16), dim3(256), 0, stream,
                       Wa_local, ba_local, Wb_local, bb_local,
                       Wa_tri, ba_tri, Wb_tri, bb_tri,
                       Wa_fuse, ba_fuse, Wb_fuse, bb_fuse, Vw, cst);

    hipLaunchKernelGGL(transpose_bf16_kernel, dim3(E_ / 32, C_ / 32, 2 * B_),
                       dim3(256), 0, stream, x0, x1, x0t, x1t);

    hipLaunchKernelGGL(mesh_fused_kernel, dim3(2048), dim3(256), 0, stream,
                       x0t, x1t, gemm, Vw, cst, out);
}

// Round 4
// 240.566 us; speedup vs baseline: 1.1333x; 1.0182x over previous
//
#include <hip/hip_runtime.h>
#include <hip/hip_bf16.h>
#include <cstdint>

#define B_ 2
#define C_ 128
#define E_ 60000

typedef unsigned int uint32_;
typedef unsigned short ushort_;
typedef float v2f __attribute__((ext_vector_type(2)));

// unpack two bf16 (dword: low = ch0, high = ch1) to packed float2
__device__ __forceinline__ v2f bp2(uint32_ v) {
    v2f r;
    r.x = __uint_as_float(v << 16);
    r.y = __uint_as_float(v & 0xffff0000u);
    return r;
}

__device__ __forceinline__ v2f vabs2(v2f a) {
    v2f r; r.x = fabsf(a.x); r.y = fabsf(a.y); return r;
}

// float -> bf16 round-to-nearest-even
__device__ __forceinline__ ushort_ f2b(float f) {
    union { float f; uint32_ u; } x; x.f = f;
    uint32_ u = x.u + 0x7fffu + ((x.u >> 16) & 1u);
    return (ushort_)(u >> 16);
}

// within-32-lane-group xor-add via ds_swizzle (and_mask 0x1F keeps halves separate)
__device__ __forceinline__ float swz_add(float v, const int pat) {
    switch (pat) {
    case 1:  return v + __int_as_float(__builtin_amdgcn_ds_swizzle(__float_as_int(v), 0x041F));
    case 2:  return v + __int_as_float(__builtin_amdgcn_ds_swizzle(__float_as_int(v), 0x081F));
    case 4:  return v + __int_as_float(__builtin_amdgcn_ds_swizzle(__float_as_int(v), 0x101F));
    case 8:  return v + __int_as_float(__builtin_amdgcn_ds_swizzle(__float_as_int(v), 0x201F));
    default: return v + __int_as_float(__builtin_amdgcn_ds_swizzle(__float_as_int(v), 0x401F));
    }
}

// ---------------------------------------------------------------------------
// Kernel 0: fold the 256->3 fuse conv into per-path weights.
// Vw layout: [p][j][s][c] flat (s=0 absorbs the local conv). cst[j] = biases.
// NOTE: needs >= 3843 threads — grid must be 16 blocks of 256 (R3 bug: was 8).
// ---------------------------------------------------------------------------
__global__ __launch_bounds__(256) void fuse_weights_kernel(
    const float* __restrict__ Wa_local, const float* __restrict__ ba_local,
    const float* __restrict__ Wb_local, const float* __restrict__ bb_local,
    const float* __restrict__ Wa_tri,  const float* __restrict__ ba_tri,
    const float* __restrict__ Wb_tri,  const float* __restrict__ bb_tri,
    const float* __restrict__ Wa_fuse, const float* __restrict__ ba_fuse,
    const float* __restrict__ Wb_fuse, const float* __restrict__ bb_fuse,
    float* __restrict__ Vw, float* __restrict__ cst)
{
    int t = blockIdx.x * 256 + threadIdx.x;
    if (t < 2 * 3 * 5 * C_) {
        int c = t & (C_ - 1);
        int r = t >> 7;          // (p*3+j)*5+s
        int s = r % 5; r /= 5;
        int j = r % 3;
        int p = r / 3;
        const float* Wf = p ? Wb_fuse : Wa_fuse;   // [3][256]
        const float* Wt = p ? Wb_tri  : Wa_tri;    // [128][128][5]
        const float* Wl = p ? Wb_local : Wa_local; // [128][128]
        float a0 = 0.f, a1 = 0.f, a2 = 0.f, a3 = 0.f;
        for (int o = 0; o < C_; o += 4) {
            a0 += Wf[j * 256 + 128 + o]     * Wt[((o)     * C_ + c) * 5 + s];
            a1 += Wf[j * 256 + 128 + o + 1] * Wt[((o + 1) * C_ + c) * 5 + s];
            a2 += Wf[j * 256 + 128 + o + 2] * Wt[((o + 2) * C_ + c) * 5 + s];
            a3 += Wf[j * 256 + 128 + o + 3] * Wt[((o + 3) * C_ + c) * 5 + s];
        }
        if (s == 0) {
            for (int o = 0; o < C_; o += 4) {
                a0 += Wf[j * 256 + o]     * Wl[(o)     * C_ + c];
                a1 += Wf[j * 256 + o + 1] * Wl[(o + 1) * C_ + c];
                a2 += Wf[j * 256 + o + 2] * Wl[(o + 2) * C_ + c];
                a3 += Wf[j * 256 + o + 3] * Wl[(o + 3) * C_ + c];
            }
        }
        Vw[t] = (a0 + a1) + (a2 + a3);
    } else if (t < 2 * 3 * 5 * C_ + 3) {
        int j = t - 2 * 3 * 5 * C_;
        float acc = ba_fuse[j] + bb_fuse[j];
        for (int o = 0; o < C_; ++o) {
            acc += Wa_fuse[j * 256 + o]       * ba_local[o]
                 + Wa_fuse[j * 256 + 128 + o] * ba_tri[o]
                 + Wb_fuse[j * 256 + o]       * bb_local[o]
                 + Wb_fuse[j * 256 + 128 + o] * bb_tri[o];
        }
        cst[j] = acc;
    }
}

// ---------------------------------------------------------------------------
// Kernel 1: transpose+quantize [B,C,E] f32 -> [B,E,C] bf16.
// 32e x 64c tile. Reads: 2x float4/lane. LDS tile[e][c] (pad 65) so the write
// phase reads 8 contiguous floats. Stores: uint4 (16 B).
// ---------------------------------------------------------------------------
__global__ __launch_bounds__(256) void transpose_bf16_kernel(
    const float* __restrict__ x0, const float* __restrict__ x1,
    ushort_* __restrict__ x0t, ushort_* __restrict__ x1t)
{
    __shared__ float tile[32][65];
    const int which = blockIdx.z >> 1;   // 0 -> x0, 1 -> x1
    const int b     = blockIdx.z & 1;
    const float* src = (which ? x1 : x0) + (size_t)b * C_ * E_;
    ushort_*     dst = (which ? x1t : x0t) + (size_t)b * E_ * C_;
    const int e0 = blockIdx.x * 32;
    const int c0 = blockIdx.y * 64;
    const int t  = threadIdx.x;
    {
        const int c  = t >> 2;          // 0..63
        const int e8 = (t & 3) * 8;     // 0,8,16,24
        const float* p = src + (size_t)(c0 + c) * E_ + e0 + e8;
        float4 v0 = *(const float4*)p;
        float4 v1 = *(const float4*)(p + 4);
        tile[e8 + 0][c] = v0.x; tile[e8 + 1][c] = v0.y;
        tile[e8 + 2][c] = v0.z; tile[e8 + 3][c] = v0.w;
        tile[e8 + 4][c] = v1.x; tile[e8 + 5][c] = v1.y;
        tile[e8 + 6][c] = v1.z; tile[e8 + 7][c] = v1.w;
    }
    __syncthreads();
    {
        const int e  = t >> 3;          // 0..31
        const int c8 = (t & 7) * 8;     // 0..56
        const float* r = &tile[e][c8];
        uint32_ w0 = (uint32_)f2b(r[0]) | ((uint32_)f2b(r[1]) << 16);
        uint32_ w1 = (uint32_)f2b(r[2]) | ((uint32_)f2b(r[3]) << 16);
        uint32_ w2 = (uint32_)f2b(r[4]) | ((uint32_)f2b(r[5]) << 16);
        uint32_ w3 = (uint32_)f2b(r[6]) | ((uint32_)f2b(r[7]) << 16);
        uint4 w; w.x = w0; w.y = w1; w.z = w2; w.w = w3;
        *(uint4*)(dst + (size_t)(e0 + e) * C_ + c0 + c8) = w;
    }
}

// ---------------------------------------------------------------------------
// Kernel 2: fused gather + features + 3-channel projection.
// Wave per edge; lane = channel pair. Packed-f32 math, saddr 32-bit offsets,
// gi prefetch, ds_swizzle reduce (xor16, shfl-xor32, select j, xor1-8).
// ---------------------------------------------------------------------------
__global__ __launch_bounds__(256, 4) void mesh_fused_kernel(
    const uint32_* __restrict__ x0t, const uint32_* __restrict__ x1t,
    const int* __restrict__ gemm, const float* __restrict__ Vw,
    const float* __restrict__ cst, float* __restrict__ out)
{
    const int lane = threadIdx.x & 63;
    const int wv   = threadIdx.x >> 6;
    const int gw   = blockIdx.x * 4 + wv;
    const int nw   = gridDim.x * 4;

    v2f w[2][3][5];
#pragma unroll
    for (int p = 0; p < 2; ++p)
#pragma unroll
        for (int j = 0; j < 3; ++j)
#pragma unroll
            for (int s = 0; s < 5; ++s)
                w[p][j][s] = *(const v2f*)(Vw + (((p * 3 + j) * 5 + s) << 7) + lane * 2);

    const int  jj     = lane >> 4;                 // 0..3
    const bool is0    = (jj == 0), is1 = (jj == 1);
    const bool writer = ((lane & 15) == 0) && (jj < 3);
    const float cj    = is0 ? cst[0] : (is1 ? cst[1] : cst[2]);
    float* obase      = out + (size_t)(jj < 3 ? jj : 2) * E_;

    const int4* g4 = (const int4*)gemm;
    const int total = B_ * E_;
    int4 gi = (gw < total) ? g4[gw] : make_int4(0, 0, 0, 0);

    for (int edge = gw; edge < total; edge += nw) {
        const int nxt = edge + nw;
        const int4 gin = (nxt < total) ? g4[nxt] : gi;   // prefetch

        const int b = (edge >= E_) ? 1 : 0;
        const int e = edge - (b ? E_ : 0);
        const uint32_* xa = x0t + (size_t)b * (E_ * 64);
        const uint32_* xb = x1t + (size_t)b * (E_ * 64);

        const uint32_ o0 = ((uint32_)e    << 6) + lane;
        const uint32_ o1 = ((uint32_)gi.x << 6) + lane;
        const uint32_ o2 = ((uint32_)gi.y << 6) + lane;
        const uint32_ o3 = ((uint32_)gi.z << 6) + lane;
        const uint32_ o4 = ((uint32_)gi.w << 6) + lane;

        const uint32_ va0 = xa[o0], va1 = xa[o1], va2 = xa[o2],
                      va3 = xa[o3], va4 = xa[o4];
        const uint32_ vb0 = xb[o0], vb1 = xb[o1], vb2 = xb[o2],
                      vb3 = xb[o3], vb4 = xb[o4];

        v2f a0 = bp2(va0), a1 = bp2(va1), a2 = bp2(va2), a3 = bp2(va3), a4 = bp2(va4);
        v2f b0 = bp2(vb0), b1 = bp2(vb1), b2 = bp2(vb2), b3 = bp2(vb3), b4 = bp2(vb4);

        v2f sa1 = a1 + a3, sa2 = a2 + a4;
        v2f da1 = vabs2(a1 - a3), da2 = vabs2(a2 - a4);
        v2f sb1 = b1 + b3, sb2 = b2 + b4;
        v2f db1 = vabs2(b1 - b3), db2 = vabs2(b2 - b4);

        v2f t0 = w[0][0][0] * a0;
        v2f t1 = w[0][1][0] * a0;
        v2f t2 = w[0][2][0] * a0;
        t0 += w[0][0][1] * sa1; t1 += w[0][1][1] * sa1; t2 += w[0][2][1] * sa1;
        t0 += w[0][0][2] * sa2; t1 += w[0][1][2] * sa2; t2 += w[0][2][2] * sa2;
        t0 += w[0][0][3] * da1; t1 += w[0][1][3] * da1; t2 += w[0][2][3] * da1;
        t0 += w[0][0][4] * da2; t1 += w[0][1][4] * da2; t2 += w[0][2][4] * da2;
        t0 += w[1][0][0] * b0;  t1 += w[1][1][0] * b0;  t2 += w[1][2][0] * b0;
        t0 += w[1][0][1] * sb1; t1 += w[1][1][1] * sb1; t2 += w[1][2][1] * sb1;
        t0 += w[1][0][2] * sb2; t1 += w[1][1][2] * sb2; t2 += w[1][2][2] * sb2;
        t0 += w[1][0][3] * db1; t1 += w[1][1][3] * db1; t2 += w[1][2][3] * db1;
        t0 += w[1][0][4] * db2; t1 += w[1][1][4] * db2; t2 += w[1][2][4] * db2;

        float r0 = t0.x + t0.y;
        float r1 = t1.x + t1.y;
        float r2 = t2.x + t2.y;

        // partial reduce: after xor16 (in-half) + xor32 (cross-half via shfl),
        // lane i holds sum over lanes == i (mod 16)
        r0 = swz_add(r0, 16);  r0 += __shfl_xor(r0, 32, 64);
        r1 = swz_add(r1, 16);  r1 += __shfl_xor(r1, 32, 64);
        r2 = swz_add(r2, 16);  r2 += __shfl_xor(r2, 32, 64);

        // each 16-lane group takes its j, then reduces its 16 mod-classes
        float val = is0 ? r0 : (is1 ? r1 : r2);
        val = swz_add(val, 1);
        val = swz_add(val, 2);
        val = swz_add(val, 4);
        val = swz_add(val, 8);

        if (writer)
            obase[(b ? 3 * E_ : 0) + e] = val + cj;

        gi = gin;
    }
}

extern "C" void kernel_launch(void* const* d_in, const int* in_sizes, int n_in,
                              void* d_out, int out_size, void* d_ws, size_t ws_size,
                              hipStream_t stream) {
    const float* x0       = (const float*)d_in[0];
    const float* x1       = (const float*)d_in[1];
    const int*   gemm     = (const int*)d_in[2];
    const float* Wa_local = (const float*)d_in[3];
    const float* ba_local = (const float*)d_in[4];
    const float* Wb_local = (const float*)d_in[5];
    const float* bb_local = (const float*)d_in[6];
    const float* Wa_tri   = (const float*)d_in[7];
    const float* ba_tri   = (const float*)d_in[8];
    const float* Wb_tri   = (const float*)d_in[9];
    const float* bb_tri   = (const float*)d_in[10];
    const float* Wa_fuse  = (const float*)d_in[11];
    const float* ba_fuse  = (const float*)d_in[12];
    const float* Wb_fuse  = (const float*)d_in[13];
    const float* bb_fuse  = (const float*)d_in[14];
    float* out = (float*)d_out;

    ushort_* x0t = (ushort_*)d_ws;                    // B*E*C bf16
    ushort_* x1t = x0t + (size_t)B_ * E_ * C_;        // B*E*C bf16
    float*   Vw  = (float*)(x1t + (size_t)B_ * E_ * C_);
    float*   cst = Vw + 2 * 3 * 5 * C_;

    hipLaunchKernelGGL(fuse_weights_kernel, dim3(16), dim3(256), 0, stream,
                       Wa_local, ba_local, Wb_local, bb_local,
                       Wa_tri, ba_tri, Wb_tri, bb_tri,
                       Wa_fuse, ba_fuse, Wb_fuse, bb_fuse, Vw, cst);

    hipLaunchKernelGGL(transpose_bf16_kernel, dim3(E_ / 32, C_ / 64, 2 * B_),
                       dim3(256), 0, stream, x0, x1, x0t, x1t);

    hipLaunchKernelGGL(mesh_fused_kernel, dim3(2048), dim3(256), 0, stream,
                       (const uint32_*)x0t, (const uint32_*)x1t, gemm, Vw, cst, out);
}

// Round 5
// 227.704 us; speedup vs baseline: 1.1973x; 1.0565x over previous
//
#include <hip/hip_runtime.h>
#include <hip/hip_bf16.h>
#include <cstdint>

#define B_ 2
#define C_ 128
#define E_ 60000

typedef unsigned int uint32_;
typedef unsigned short ushort_;
typedef float v2f __attribute__((ext_vector_type(2)));

// unpack two bf16 (dword: low = ch0, high = ch1) to packed float2
__device__ __forceinline__ v2f bp2(uint32_ v) {
    v2f r;
    r.x = __uint_as_float(v << 16);
    r.y = __uint_as_float(v & 0xffff0000u);
    return r;
}

__device__ __forceinline__ v2f vabs2(v2f a) {
    v2f r; r.x = fabsf(a.x); r.y = fabsf(a.y); return r;
}

// float -> bf16 round-to-nearest-even
__device__ __forceinline__ ushort_ f2b(float f) {
    union { float f; uint32_ u; } x; x.f = f;
    uint32_ u = x.u + 0x7fffu + ((x.u >> 16) & 1u);
    return (ushort_)(u >> 16);
}

// within-32-lane-group xor-add via ds_swizzle (and_mask 0x1F keeps halves separate)
__device__ __forceinline__ float swz_add(float v, const int pat) {
    switch (pat) {
    case 1:  return v + __int_as_float(__builtin_amdgcn_ds_swizzle(__float_as_int(v), 0x041F));
    case 2:  return v + __int_as_float(__builtin_amdgcn_ds_swizzle(__float_as_int(v), 0x081F));
    case 4:  return v + __int_as_float(__builtin_amdgcn_ds_swizzle(__float_as_int(v), 0x101F));
    case 8:  return v + __int_as_float(__builtin_amdgcn_ds_swizzle(__float_as_int(v), 0x201F));
    default: return v + __int_as_float(__builtin_amdgcn_ds_swizzle(__float_as_int(v), 0x401F));
    }
}

// ---------------------------------------------------------------------------
// Kernel 0: fold the 256->3 fuse conv into per-path weights (wave-parallel).
// Blocks 0..14: 60 waves; wave = (p,j, chunk of 64 flat f=c*5+s indices).
// Wt flat index = o*640 + f  -> fully coalesced 256 B loads per wave.
// Wf[j*256+128+o] is wave-uniform -> scalar broadcast. 4-way unrolled MLP.
// Block 15: cst (3 serial threads, tiny).
// ---------------------------------------------------------------------------
__global__ __launch_bounds__(256) void fuse_weights_kernel(
    const float* __restrict__ Wa_local, const float* __restrict__ ba_local,
    const float* __restrict__ Wb_local, const float* __restrict__ bb_local,
    const float* __restrict__ Wa_tri,  const float* __restrict__ ba_tri,
    const float* __restrict__ Wb_tri,  const float* __restrict__ bb_tri,
    const float* __restrict__ Wa_fuse, const float* __restrict__ ba_fuse,
    const float* __restrict__ Wb_fuse, const float* __restrict__ bb_fuse,
    float* __restrict__ Vw, float* __restrict__ cst)
{
    const int lane = threadIdx.x & 63;
    if (blockIdx.x < 15) {
        const int wid   = blockIdx.x * 4 + (threadIdx.x >> 6); // 0..59
        const int pj    = wid / 10;                            // 0..5
        const int chunk = wid % 10;                            // 0..9
        const int p = pj / 3, j = pj % 3;
        const int f = chunk * 64 + lane;                       // 0..639 = c*5+s
        const float* Wf = p ? Wb_fuse : Wa_fuse;   // [3][256]
        const float* Wt = p ? Wb_tri  : Wa_tri;    // [128][128][5] flat o*640+f
        const float* Wl = p ? Wb_local : Wa_local; // [128][128]
        float a0 = 0.f, a1 = 0.f, a2 = 0.f, a3 = 0.f;
        for (int o = 0; o < C_; o += 4) {
            a0 += Wf[j * 256 + 128 + o]     * Wt[(o)     * 640 + f];
            a1 += Wf[j * 256 + 128 + o + 1] * Wt[(o + 1) * 640 + f];
            a2 += Wf[j * 256 + 128 + o + 2] * Wt[(o + 2) * 640 + f];
            a3 += Wf[j * 256 + 128 + o + 3] * Wt[(o + 3) * 640 + f];
        }
        float acc = (a0 + a1) + (a2 + a3);
        const int s = f % 5, c = f / 5;
        if (s == 0) {   // absorb the local conv into the s=0 slot
            float b0 = 0.f, b1 = 0.f, b2 = 0.f, b3 = 0.f;
            for (int o = 0; o < C_; o += 4) {
                b0 += Wf[j * 256 + o]     * Wl[(o)     * C_ + c];
                b1 += Wf[j * 256 + o + 1] * Wl[(o + 1) * C_ + c];
                b2 += Wf[j * 256 + o + 2] * Wl[(o + 2) * C_ + c];
                b3 += Wf[j * 256 + o + 3] * Wl[(o + 3) * C_ + c];
            }
            acc += (b0 + b1) + (b2 + b3);
        }
        Vw[(pj * 5 + s) * C_ + c] = acc;
    } else {
        if (threadIdx.x < 3) {
            int j = threadIdx.x;
            float acc = ba_fuse[j] + bb_fuse[j];
            for (int o = 0; o < C_; ++o) {
                acc += Wa_fuse[j * 256 + o]       * ba_local[o]
                     + Wa_fuse[j * 256 + 128 + o] * ba_tri[o]
                     + Wb_fuse[j * 256 + o]       * bb_local[o]
                     + Wb_fuse[j * 256 + 128 + o] * bb_tri[o];
            }
            cst[j] = acc;
        }
    }
}

// ---------------------------------------------------------------------------
// Kernel 1: transpose+quantize [B,C,E] f32 -> [B,E,C] bf16 (unchanged R4).
// ---------------------------------------------------------------------------
__global__ __launch_bounds__(256) void transpose_bf16_kernel(
    const float* __restrict__ x0, const float* __restrict__ x1,
    ushort_* __restrict__ x0t, ushort_* __restrict__ x1t)
{
    __shared__ float tile[32][65];
    const int which = blockIdx.z >> 1;   // 0 -> x0, 1 -> x1
    const int b     = blockIdx.z & 1;
    const float* src = (which ? x1 : x0) + (size_t)b * C_ * E_;
    ushort_*     dst = (which ? x1t : x0t) + (size_t)b * E_ * C_;
    const int e0 = blockIdx.x * 32;
    const int c0 = blockIdx.y * 64;
    const int t  = threadIdx.x;
    {
        const int c  = t >> 2;          // 0..63
        const int e8 = (t & 3) * 8;     // 0,8,16,24
        const float* p = src + (size_t)(c0 + c) * E_ + e0 + e8;
        float4 v0 = *(const float4*)p;
        float4 v1 = *(const float4*)(p + 4);
        tile[e8 + 0][c] = v0.x; tile[e8 + 1][c] = v0.y;
        tile[e8 + 2][c] = v0.z; tile[e8 + 3][c] = v0.w;
        tile[e8 + 4][c] = v1.x; tile[e8 + 5][c] = v1.y;
        tile[e8 + 6][c] = v1.z; tile[e8 + 7][c] = v1.w;
    }
    __syncthreads();
    {
        const int e  = t >> 3;          // 0..31
        const int c8 = (t & 7) * 8;     // 0..56
        const float* r = &tile[e][c8];
        uint32_ w0 = (uint32_)f2b(r[0]) | ((uint32_)f2b(r[1]) << 16);
        uint32_ w1 = (uint32_)f2b(r[2]) | ((uint32_)f2b(r[3]) << 16);
        uint32_ w2 = (uint32_)f2b(r[4]) | ((uint32_)f2b(r[5]) << 16);
        uint32_ w3 = (uint32_)f2b(r[6]) | ((uint32_)f2b(r[7]) << 16);
        uint4 w; w.x = w0; w.y = w1; w.z = w2; w.w = w3;
        *(uint4*)(dst + (size_t)(e0 + e) * C_ + c0 + c8) = w;
    }
}

// ---------------------------------------------------------------------------
// Kernel 2: fused gather + features + 3-channel projection.
// TWO edges (adjacent e, same batch since E is even) per wave-iteration:
// 20 outstanding gathers for latency hiding, shared index prefetch, and the
// two writer stores merge into one float2.
// ---------------------------------------------------------------------------
__global__ __launch_bounds__(256, 4) void mesh_fused_kernel(
    const uint32_* __restrict__ x0t, const uint32_* __restrict__ x1t,
    const int* __restrict__ gemm, const float* __restrict__ Vw,
    const float* __restrict__ cst, float* __restrict__ out)
{
    const int lane = threadIdx.x & 63;
    const int wv   = threadIdx.x >> 6;
    const int gw   = blockIdx.x * 4 + wv;
    const int nw   = gridDim.x * 4;

    v2f w[2][3][5];
#pragma unroll
    for (int p = 0; p < 2; ++p)
#pragma unroll
        for (int j = 0; j < 3; ++j)
#pragma unroll
            for (int s = 0; s < 5; ++s)
                w[p][j][s] = *(const v2f*)(Vw + (((p * 3 + j) * 5 + s) << 7) + lane * 2);

    const int  jj     = lane >> 4;                 // 0..3
    const bool is0    = (jj == 0), is1 = (jj == 1);
    const bool writer = ((lane & 15) == 0) && (jj < 3);
    const float cj    = is0 ? cst[0] : (is1 ? cst[1] : cst[2]);
    float* obase      = out + (size_t)(jj < 3 ? jj : 2) * E_;

    const int4* g4 = (const int4*)gemm;
    const int npair = (B_ * E_) / 2;

    int4 giA = make_int4(0, 0, 0, 0), giB = giA;
    if (gw < npair) { giA = g4[2 * gw]; giB = g4[2 * gw + 1]; }

    for (int pair = gw; pair < npair; pair += nw) {
        const int nxt = pair + nw;
        const int4 gA = giA, gB = giB;
        if (nxt < npair) { giA = g4[2 * nxt]; giB = g4[2 * nxt + 1]; }  // prefetch

        const int e0 = 2 * pair;
        const int b  = (e0 >= E_) ? 1 : 0;
        const int e  = e0 - (b ? E_ : 0);
        const uint32_* xa = x0t + (size_t)b * (E_ * 64);
        const uint32_* xb = x1t + (size_t)b * (E_ * 64);

        const uint32_ sA = ((uint32_)e << 6) + lane;
        const uint32_ sB = sA + 64;
        const uint32_ oA1 = ((uint32_)gA.x << 6) + lane;
        const uint32_ oA2 = ((uint32_)gA.y << 6) + lane;
        const uint32_ oA3 = ((uint32_)gA.z << 6) + lane;
        const uint32_ oA4 = ((uint32_)gA.w << 6) + lane;
        const uint32_ oB1 = ((uint32_)gB.x << 6) + lane;
        const uint32_ oB2 = ((uint32_)gB.y << 6) + lane;
        const uint32_ oB3 = ((uint32_)gB.z << 6) + lane;
        const uint32_ oB4 = ((uint32_)gB.w << 6) + lane;

        // 20 independent gathers issued together
        const uint32_ A0 = xa[sA],  A1 = xa[oA1], A2 = xa[oA2], A3 = xa[oA3], A4 = xa[oA4];
        const uint32_ C0 = xb[sA],  C1 = xb[oA1], C2 = xb[oA2], C3 = xb[oA3], C4 = xb[oA4];
        const uint32_ D0 = xa[sB],  D1 = xa[oB1], D2 = xa[oB2], D3 = xa[oB3], D4 = xa[oB4];
        const uint32_ F0 = xb[sB],  F1 = xb[oB1], F2 = xb[oB2], F3 = xb[oB3], F4 = xb[oB4];

        // ---- edge A ----
        float rA0, rA1, rA2;
        {
            v2f a0 = bp2(A0), a1 = bp2(A1), a2 = bp2(A2), a3 = bp2(A3), a4 = bp2(A4);
            v2f b0 = bp2(C0), b1 = bp2(C1), b2 = bp2(C2), b3 = bp2(C3), b4 = bp2(C4);
            v2f sa1 = a1 + a3, sa2 = a2 + a4;
            v2f da1 = vabs2(a1 - a3), da2 = vabs2(a2 - a4);
            v2f sb1 = b1 + b3, sb2 = b2 + b4;
            v2f db1 = vabs2(b1 - b3), db2 = vabs2(b2 - b4);
            v2f t0 = w[0][0][0] * a0, t1 = w[0][1][0] * a0, t2 = w[0][2][0] * a0;
            t0 += w[0][0][1] * sa1; t1 += w[0][1][1] * sa1; t2 += w[0][2][1] * sa1;
            t0 += w[0][0][2] * sa2; t1 += w[0][1][2] * sa2; t2 += w[0][2][2] * sa2;
            t0 += w[0][0][3] * da1; t1 += w[0][1][3] * da1; t2 += w[0][2][3] * da1;
            t0 += w[0][0][4] * da2; t1 += w[0][1][4] * da2; t2 += w[0][2][4] * da2;
            t0 += w[1][0][0] * b0;  t1 += w[1][1][0] * b0;  t2 += w[1][2][0] * b0;
            t0 += w[1][0][1] * sb1; t1 += w[1][1][1] * sb1; t2 += w[1][2][1] * sb1;
            t0 += w[1][0][2] * sb2; t1 += w[1][1][2] * sb2; t2 += w[1][2][2] * sb2;
            t0 += w[1][0][3] * db1; t1 += w[1][1][3] * db1; t2 += w[1][2][3] * db1;
            t0 += w[1][0][4] * db2; t1 += w[1][1][4] * db2; t2 += w[1][2][4] * db2;
            rA0 = t0.x + t0.y; rA1 = t1.x + t1.y; rA2 = t2.x + t2.y;
        }
        // ---- edge B ----
        float rB0, rB1, rB2;
        {
            v2f a0 = bp2(D0), a1 = bp2(D1), a2 = bp2(D2), a3 = bp2(D3), a4 = bp2(D4);
            v2f b0 = bp2(F0), b1 = bp2(F1), b2 = bp2(F2), b3 = bp2(F3), b4 = bp2(F4);
            v2f sa1 = a1 + a3, sa2 = a2 + a4;
            v2f da1 = vabs2(a1 - a3), da2 = vabs2(a2 - a4);
            v2f sb1 = b1 + b3, sb2 = b2 + b4;
            v2f db1 = vabs2(b1 - b3), db2 = vabs2(b2 - b4);
            v2f t0 = w[0][0][0] * a0, t1 = w[0][1][0] * a0, t2 = w[0][2][0] * a0;
            t0 += w[0][0][1] * sa1; t1 += w[0][1][1] * sa1; t2 += w[0][2][1] * sa1;
            t0 += w[0][0][2] * sa2; t1 += w[0][1][2] * sa2; t2 += w[0][2][2] * sa2;
            t0 += w[0][0][3] * da1; t1 += w[0][1][3] * da1; t2 += w[0][2][3] * da1;
            t0 += w[0][0][4] * da2; t1 += w[0][1][4] * da2; t2 += w[0][2][4] * da2;
            t0 += w[1][0][0] * b0;  t1 += w[1][1][0] * b0;  t2 += w[1][2][0] * b0;
            t0 += w[1][0][1] * sb1; t1 += w[1][1][1] * sb1; t2 += w[1][2][1] * sb1;
            t0 += w[1][0][2] * sb2; t1 += w[1][1][2] * sb2; t2 += w[1][2][2] * sb2;
            t0 += w[1][0][3] * db1; t1 += w[1][1][3] * db1; t2 += w[1][2][3] * db1;
            t0 += w[1][0][4] * db2; t1 += w[1][1][4] * db2; t2 += w[1][2][4] * db2;
            rB0 = t0.x + t0.y; rB1 = t1.x + t1.y; rB2 = t2.x + t2.y;
        }

        // partial reduce (independent A/B chains interleaved for pipe overlap)
        rA0 = swz_add(rA0, 16); rB0 = swz_add(rB0, 16);
        rA1 = swz_add(rA1, 16); rB1 = swz_add(rB1, 16);
        rA2 = swz_add(rA2, 16); rB2 = swz_add(rB2, 16);
        rA0 += __shfl_xor(rA0, 32, 64); rB0 += __shfl_xor(rB0, 32, 64);
        rA1 += __shfl_xor(rA1, 32, 64); rB1 += __shfl_xor(rB1, 32, 64);
        rA2 += __shfl_xor(rA2, 32, 64); rB2 += __shfl_xor(rB2, 32, 64);

        float vA = is0 ? rA0 : (is1 ? rA1 : rA2);
        float vB = is0 ? rB0 : (is1 ? rB1 : rB2);
        vA = swz_add(vA, 1); vB = swz_add(vB, 1);
        vA = swz_add(vA, 2); vB = swz_add(vB, 2);
        vA = swz_add(vA, 4); vB = swz_add(vB, 4);
        vA = swz_add(vA, 8); vB = swz_add(vB, 8);

        if (writer) {
            float2 st; st.x = vA + cj; st.y = vB + cj;
            *(float2*)(obase + (b ? 3 * E_ : 0) + e) = st;   // e is even -> aligned
        }
    }
}

extern "C" void kernel_launch(void* const* d_in, const int* in_sizes, int n_in,
                              void* d_out, int out_size, void* d_ws, size_t ws_size,
                              hipStream_t stream) {
    const float* x0       = (const float*)d_in[0];
    const float* x1       = (const float*)d_in[1];
    const int*   gemm     = (const int*)d_in[2];
    const float* Wa_local = (const float*)d_in[3];
    const float* ba_local = (const float*)d_in[4];
    const float* Wb_local = (const float*)d_in[5];
    const float* bb_local = (const float*)d_in[6];
    const float* Wa_tri   = (const float*)d_in[7];
    const float* ba_tri   = (const float*)d_in[8];
    const float* Wb_tri   = (const float*)d_in[9];
    const float* bb_tri   = (const float*)d_in[10];
    const float* Wa_fuse  = (const float*)d_in[11];
    const float* ba_fuse  = (const float*)d_in[12];
    const float* Wb_fuse  = (const float*)d_in[13];
    const float* bb_fuse  = (const float*)d_in[14];
    float* out = (float*)d_out;

    ushort_* x0t = (ushort_*)d_ws;                    // B*E*C bf16
    ushort_* x1t = x0t + (size_t)B_ * E_ * C_;        // B*E*C bf16
    float*   Vw  = (float*)(x1t + (size_t)B_ * E_ * C_);
    float*   cst = Vw + 2 * 3 * 5 * C_;

    hipLaunchKernelGGL(fuse_weights_kernel, dim3(16), dim3(256), 0, stream,
                       Wa_local, ba_local, Wb_local, bb_local,
                       Wa_tri, ba_tri, Wb_tri, bb_tri,
                       Wa_fuse, ba_fuse, Wb_fuse, bb_fuse, Vw, cst);

    hipLaunchKernelGGL(transpose_bf16_kernel, dim3(E_ / 32, C_ / 64, 2 * B_),
                       dim3(256), 0, stream, x0, x1, x0t, x1t);

    hipLaunchKernelGGL(mesh_fused_kernel, dim3(2048), dim3(256), 0, stream,
                       (const uint32_*)x0t, (const uint32_*)x1t, gemm, Vw, cst, out);
}